// Round 2
// baseline (179.921 us; speedup 1.0000x reference)
//
#include <hip/hip_runtime.h>
#include <stdint.h>

namespace {
constexpr int BATCH  = 512;
constexpr int CBS    = 320;       // combined batch size
constexpr int R      = 64;        // rank
constexpr int K      = 4096;
constexpr int NADAPT = 80;
constexpr int GRP    = 4;         // combos per block (wid-sorted -> usually same wid)
constexpr int NGRP   = CBS / GRP; // 80
constexpr int SPLIT  = 16;        // k-slices; grid = 80*16 = 1280 = 5 * 256 CUs exactly
constexpr int KS     = K / SPLIT; // 256 k per block
constexpr int KW     = KS / 4;    // 64 k per wave
constexpr int NT     = 256;       // 4 waves

// ws layout: perm[320] ints at 0; x_bf16[512][4096] at byte 4096
constexpr size_t WS_X_OFF  = 4096;
constexpr size_t WS_NEEDED = WS_X_OFF + (size_t)BATCH * K * 2;  // ~4.2 MiB

__device__ inline uint16_t f2bf(float f) {   // RNE fp32 -> bf16
    uint32_t u = __float_as_uint(f);
    u += 0x7fffu + ((u >> 16) & 1u);
    return (uint16_t)(u >> 16);
}
__device__ inline float bflo(uint32_t u) { return __uint_as_float(u << 16); }
__device__ inline float bfhi(uint32_t u) { return __uint_as_float(u & 0xffff0000u); }
}

// ---- pre-pass (fused): block 0 = wid-sort; blocks 1..2048 = x fp32->bf16;
//      trailing blocks zero `out` ----
__global__ __launch_bounds__(256)
void prep(const float* __restrict__ x, uint16_t* __restrict__ xb,
          const int* __restrict__ wids, int* __restrict__ perm,
          float* __restrict__ out, int out_size)
{
    const int bid = blockIdx.x;
    const int t   = threadIdx.x;
    if (bid == 0) {
        __shared__ int hist[NADAPT];
        __shared__ int offs[NADAPT];
        if (t < NADAPT) hist[t] = 0;
        __syncthreads();
        for (int c = t; c < CBS; c += 256) atomicAdd(&hist[wids[c]], 1);
        __syncthreads();
        if (t == 0) {
            int run = 0;
            for (int i = 0; i < NADAPT; ++i) { offs[i] = run; run += hist[i]; }
        }
        __syncthreads();
        for (int c = t; c < CBS; c += 256) {
            const int pos = atomicAdd(&offs[wids[c]], 1);
            perm[pos] = c;
        }
    } else if (bid <= BATCH * K / 1024) {          // 2048 cvt blocks
        const int i = (bid - 1) * 256 + t;         // over BATCH*K/4 float4s
        const float4 v = ((const float4*)x)[i];
        ushort4 o;
        o.x = f2bf(v.x); o.y = f2bf(v.y); o.z = f2bf(v.z); o.w = f2bf(v.w);
        ((ushort4*)xb)[i] = o;
    } else {                                       // zero out[]
        const int i4 = (bid - (1 + BATCH * K / 1024)) * 256 + t;
        const int e  = i4 * 4;
        if (e + 3 < out_size) {
            ((float4*)out)[i4] = make_float4(0.f, 0.f, 0.f, 0.f);
        } else {
            for (int q = e; q < out_size; ++q) out[q] = 0.f;
        }
    }
}

// ---- main: block (g, s) = 4 wid-sorted combos x k-slice s. No LDS, no barriers.
// Lane owns output r (lane = r): x[tok_r, k..] is per-lane contiguous (uint4 = 8
// bf16 per load, one L1 line per (lane,combo)); A[k, 0..63] is one coalesced
// 256 B dword-load per k, shared in-register across all 4 combos when the group
// is wid-uniform (common case: avg 4 combos/adapter). k-reduction is fully
// lane-local -> no shuffles; one coalesced atomicAdd per combo per wave.
__global__ __launch_bounds__(NT)
void lora_main(const int* __restrict__ xids,
               const int* __restrict__ wids,
               const float* __restrict__ A,
               const uint16_t* __restrict__ xb,
               const int* __restrict__ perm,
               float* __restrict__ out)
{
    const int bid = blockIdx.x;
    const int g   = bid >> 4;          // group of 4 sorted combos
    const int s   = bid & 15;          // k-slice -> XCD = bid%8 stable per slice
    const int t   = threadIdx.x;
    const int wv  = t >> 6;
    const int r   = t & 63;            // lane owns this output r
    const int k0  = s * KS + wv * KW;  // wave's k-range [k0, k0+64)

    const int c0 = perm[GRP * g + 0], c1 = perm[GRP * g + 1],
              c2 = perm[GRP * g + 2], c3 = perm[GRP * g + 3];
    const int w0 = wids[c0], w1 = wids[c1], w2 = wids[c2], w3 = wids[c3];

    const uint16_t* __restrict__ xp0 = xb + (size_t)xids[c0 * R + r] * K + k0;
    const uint16_t* __restrict__ xp1 = xb + (size_t)xids[c1 * R + r] * K + k0;
    const uint16_t* __restrict__ xp2 = xb + (size_t)xids[c2 * R + r] * K + k0;
    const uint16_t* __restrict__ xp3 = xb + (size_t)xids[c3 * R + r] * K + k0;

    const size_t kb = (size_t)k0 * R + r;
    const float* __restrict__ A0 = A + (size_t)w0 * (K * R) + kb;
    const float* __restrict__ A1 = A + (size_t)w1 * (K * R) + kb;
    const float* __restrict__ A2 = A + (size_t)w2 * (K * R) + kb;
    const float* __restrict__ A3 = A + (size_t)w3 * (K * R) + kb;

    float acc0 = 0.f, acc1 = 0.f, acc2 = 0.f, acc3 = 0.f;

#define FMA8(ACC, V, AP) do {                                              \
        ACC = fmaf(bflo((V).x), (AP)[0], ACC);                             \
        ACC = fmaf(bfhi((V).x), (AP)[1], ACC);                             \
        ACC = fmaf(bflo((V).y), (AP)[2], ACC);                             \
        ACC = fmaf(bfhi((V).y), (AP)[3], ACC);                             \
        ACC = fmaf(bflo((V).z), (AP)[4], ACC);                             \
        ACC = fmaf(bfhi((V).z), (AP)[5], ACC);                             \
        ACC = fmaf(bflo((V).w), (AP)[6], ACC);                             \
        ACC = fmaf(bfhi((V).w), (AP)[7], ACC);                             \
    } while (0)

    if (w0 == w3) {
        // uniform-wid group: A loaded once, used 4x (in-register sharing)
#pragma unroll 2
        for (int kk = 0; kk < KW; kk += 8) {
            const uint4 v0 = *(const uint4*)(xp0 + kk);
            const uint4 v1 = *(const uint4*)(xp1 + kk);
            const uint4 v2 = *(const uint4*)(xp2 + kk);
            const uint4 v3 = *(const uint4*)(xp3 + kk);
            float a[8];
#pragma unroll
            for (int q = 0; q < 8; ++q) a[q] = A0[(size_t)(kk + q) * R];
            FMA8(acc0, v0, a);
            FMA8(acc1, v1, a);
            FMA8(acc2, v2, a);
            FMA8(acc3, v3, a);
        }
    } else {
        // mixed-wid group (rare): per-combo A loads; duplicates hit L1
#pragma unroll 2
        for (int kk = 0; kk < KW; kk += 8) {
            const uint4 v0 = *(const uint4*)(xp0 + kk);
            const uint4 v1 = *(const uint4*)(xp1 + kk);
            const uint4 v2 = *(const uint4*)(xp2 + kk);
            const uint4 v3 = *(const uint4*)(xp3 + kk);
            float a0[8], a1[8], a2[8], a3[8];
#pragma unroll
            for (int q = 0; q < 8; ++q) {
                const size_t o = (size_t)(kk + q) * R;
                a0[q] = A0[o]; a1[q] = A1[o]; a2[q] = A2[o]; a3[q] = A3[o];
            }
            FMA8(acc0, v0, a0);
            FMA8(acc1, v1, a1);
            FMA8(acc2, v2, a2);
            FMA8(acc3, v3, a3);
        }
    }
#undef FMA8

    atomicAdd(&out[c0 * R + r], acc0);
    atomicAdd(&out[c1 * R + r], acc1);
    atomicAdd(&out[c2 * R + r], acc2);
    atomicAdd(&out[c3 * R + r], acc3);
}

// ---- fallback (ws too small): fp32 x from global, LDS transpose, no perm ----
__global__ __launch_bounds__(NT)
void lora_fallback(const float* __restrict__ x,
                   const int*   __restrict__ xids,
                   const int*   __restrict__ wids,
                   const float* __restrict__ A,
                   float*       __restrict__ out)
{
    constexpr int FKS = 512, FTK = 64, FNT_TILES = 8, FNW = 4;
    __shared__ float xsf[FTK * R];
    __shared__ float red[FNW * R];
    const int bid  = blockIdx.x;
    const int c    = bid >> 3;
    const int s    = bid & 7;
    const int t    = threadIdx.x;
    const int wave = t >> 6;
    const int lane = t & 63;
    const int r4   = lane & 15;
    const int kq   = lane >> 4;
    const int wid  = wids[c];
    const float* __restrict__ Aw = A + (size_t)wid * (K * R);
    const int rw  = t >> 2;
    const int jq  = t & 3;
    const int tok = xids[c * R + rw];
    const float* __restrict__ xrow = x + (size_t)tok * K + s * FKS + jq * 16;
    float4 acc = make_float4(0.f, 0.f, 0.f, 0.f);
    float4 pv[4];
    {
        const float4* src = (const float4*)xrow;
#pragma unroll
        for (int ii = 0; ii < 4; ++ii) pv[ii] = src[ii];
    }
    for (int tile = 0; tile < FNT_TILES; ++tile) {
#pragma unroll
        for (int ii = 0; ii < 4; ++ii) {
            const int kk = jq * 16 + ii * 4;
            xsf[(kk + 0) * R + rw] = pv[ii].x;
            xsf[(kk + 1) * R + rw] = pv[ii].y;
            xsf[(kk + 2) * R + rw] = pv[ii].z;
            xsf[(kk + 3) * R + rw] = pv[ii].w;
        }
        __syncthreads();
        if (tile + 1 < FNT_TILES) {
            const float4* src = (const float4*)(xrow + (tile + 1) * FTK);
#pragma unroll
            for (int ii = 0; ii < 4; ++ii) pv[ii] = src[ii];
        }
        const int kw = wave * 16 + kq;
        const float* __restrict__ Ap =
            Aw + (size_t)(s * FKS + tile * FTK + kw) * R + 4 * r4;
#pragma unroll
        for (int i = 0; i < 4; ++i) {
            float4 av = *(const float4*)(Ap + (size_t)(4 * i) * R);
            float4 xv = *(const float4*)(&xsf[(kw + 4 * i) * R + 4 * r4]);
            acc.x = fmaf(xv.x, av.x, acc.x);
            acc.y = fmaf(xv.y, av.y, acc.y);
            acc.z = fmaf(xv.z, av.z, acc.z);
            acc.w = fmaf(xv.w, av.w, acc.w);
        }
        __syncthreads();
    }
#pragma unroll
    for (int m = 16; m < 64; m <<= 1) {
        acc.x += __shfl_xor(acc.x, m, 64);
        acc.y += __shfl_xor(acc.y, m, 64);
        acc.z += __shfl_xor(acc.z, m, 64);
        acc.w += __shfl_xor(acc.w, m, 64);
    }
    if (kq == 0) {
        float* rd = &red[wave * R + 4 * r4];
        rd[0] = acc.x; rd[1] = acc.y; rd[2] = acc.z; rd[3] = acc.w;
    }
    __syncthreads();
    if (wave == 0) {
        float sum = red[lane] + red[R + lane] + red[2 * R + lane] + red[3 * R + lane];
        atomicAdd(&out[c * R + lane], sum);
    }
}

extern "C" void kernel_launch(void* const* d_in, const int* in_sizes, int n_in,
                              void* d_out, int out_size, void* d_ws, size_t ws_size,
                              hipStream_t stream)
{
    (void)in_sizes; (void)n_in;
    const float* x    = (const float*)d_in[0];
    const int*   xids = (const int*)d_in[1];
    const int*   wids = (const int*)d_in[2];
    const float* A    = (const float*)d_in[3];
    float* out        = (float*)d_out;

    if (ws_size >= WS_NEEDED) {
        int*      perm = (int*)d_ws;
        uint16_t* xbw  = (uint16_t*)((char*)d_ws + WS_X_OFF);
        const int ncvt = BATCH * K / 1024;              // 2048
        const int nz   = (out_size + 1023) / 1024;      // out-zero blocks
        hipLaunchKernelGGL(prep, dim3(1 + ncvt + nz), dim3(256), 0, stream,
                           x, xbw, wids, perm, out, out_size);
        hipLaunchKernelGGL(lora_main, dim3(NGRP * SPLIT), dim3(NT), 0, stream,
                           xids, wids, A, xbw, perm, out);
    } else {
        hipMemsetAsync(out, 0, (size_t)out_size * sizeof(float), stream);
        hipLaunchKernelGGL(lora_fallback, dim3(CBS * 8), dim3(NT), 0, stream,
                           x, xids, wids, A, out);
    }
}

// Round 3
// 159.961 us; speedup vs baseline: 1.1248x; 1.1248x over previous
//
#include <hip/hip_runtime.h>
#include <stdint.h>

namespace {
constexpr int BATCH  = 512;
constexpr int CBS    = 320;       // combined batch size
constexpr int R      = 64;        // rank
constexpr int K      = 4096;
constexpr int NADAPT = 80;
constexpr int GRP    = 4;         // combos per block (wid-sorted: usually same wid)
constexpr int NGRP   = CBS / GRP; // 80
constexpr int SPLIT  = 16;        // k-slices; grid = 80*16 = 1280
constexpr int KS     = K / SPLIT; // 256 k per block
constexpr int TK     = 32;        // k per LDS tile
constexpr int NTILE  = KS / TK;   // 8
constexpr int NT     = 256;       // 4 waves

// ws layout: perm[320] ints at 0; x_bf16[512][4096] at byte 4096
constexpr size_t WS_X_OFF  = 4096;
constexpr size_t WS_NEEDED = WS_X_OFF + (size_t)BATCH * K * 2;  // ~4.2 MiB

__device__ inline uint16_t f2bf(float f) {   // RNE fp32 -> bf16
    uint32_t u = __float_as_uint(f);
    u += 0x7fffu + ((u >> 16) & 1u);
    return (uint16_t)(u >> 16);
}
__device__ inline float bflo(uint32_t u) { return __uint_as_float(u << 16); }
__device__ inline float bfhi(uint32_t u) { return __uint_as_float(u & 0xffff0000u); }
}

// ---- pre-pass (fused): block 0 = wid-sort; blocks 1..2048 = x fp32->bf16;
//      trailing blocks zero `out` ----
__global__ __launch_bounds__(256)
void prep(const float* __restrict__ x, uint16_t* __restrict__ xb,
          const int* __restrict__ wids, int* __restrict__ perm,
          float* __restrict__ out, int out_size)
{
    const int bid = blockIdx.x;
    const int t   = threadIdx.x;
    if (bid == 0) {
        __shared__ int hist[NADAPT];
        __shared__ int offs[NADAPT];
        if (t < NADAPT) hist[t] = 0;
        __syncthreads();
        for (int c = t; c < CBS; c += 256) atomicAdd(&hist[wids[c]], 1);
        __syncthreads();
        if (t == 0) {
            int run = 0;
            for (int i = 0; i < NADAPT; ++i) { offs[i] = run; run += hist[i]; }
        }
        __syncthreads();
        for (int c = t; c < CBS; c += 256) {
            const int pos = atomicAdd(&offs[wids[c]], 1);
            perm[pos] = c;
        }
    } else if (bid <= BATCH * K / 1024) {          // 2048 cvt blocks
        const int i = (bid - 1) * 256 + t;         // over BATCH*K/4 float4s
        const float4 v = ((const float4*)x)[i];
        ushort4 o;
        o.x = f2bf(v.x); o.y = f2bf(v.y); o.z = f2bf(v.z); o.w = f2bf(v.w);
        ((ushort4*)xb)[i] = o;
    } else {                                       // zero out[]
        const int i4 = (bid - (1 + BATCH * K / 1024)) * 256 + t;
        const int e  = i4 * 4;
        if (e + 3 < out_size) {
            ((float4*)out)[i4] = make_float4(0.f, 0.f, 0.f, 0.f);
        } else {
            for (int q = e; q < out_size; ++q) out[q] = 0.f;
        }
    }
}

// ---- main: block (g, s) = 4 wid-sorted combos x 256-k slice ----
// Staging (per 32-k tile): thread (cc = wave, row l = lane) loads ONE 64 B line
// of its token row (4 x uint4) and stores 4 x ds_write_b128 into
// xs[c][j][r][0..3] (j = k-pair-quad). The loaded uint4 IS the 4 bf16 k-pairs:
// no repack. Writes/reads both land 2 lanes/bank (free, per m136).
// Compute: lane = r owns output r; wave wv covers pair-quad j = wv (8 k/tile).
// Per tile per lane: 1 ds_read_b128 per combo + 8 coalesced A dwords (one
// 256 B row per instr), A shared in-register across all 4 combos when the
// group is wid-uniform. k-reduction lane-local; cross-wave via 4 KB red[].
__global__ __launch_bounds__(NT, 4)
void lora_main(const int* __restrict__ xids,
               const int* __restrict__ wids,
               const float* __restrict__ A,
               const uint16_t* __restrict__ xb,
               const int* __restrict__ perm,
               float* __restrict__ out)
{
    __shared__ __align__(16) uint32_t xs[2][GRP * 1024];  // 2 x 16 KiB
    __shared__ float red[4 * GRP * 64];                   // 4 KiB

    const int bid = blockIdx.x;
    const int g   = bid >> 4;
    const int s   = bid & 15;
    const int t   = threadIdx.x;
    const int wv  = t >> 6;
    const int r   = t & 63;

    const int c0 = perm[GRP * g + 0], c1 = perm[GRP * g + 1],
              c2 = perm[GRP * g + 2], c3 = perm[GRP * g + 3];
    const int w0 = wids[c0], w1 = wids[c1], w2 = wids[c2], w3 = wids[c3];

    // staging role: combo cc = wv, token row l = r
    const int cc = wv;
    const int ccombo = (wv == 0) ? c0 : (wv == 1) ? c1 : (wv == 2) ? c2 : c3;
    const uint16_t* __restrict__ xrow =
        xb + (size_t)xids[ccombo * R + r] * K + s * KS;

    // compute-side A bases (per combo; only A0 used when uniform)
    const size_t koff = (size_t)(s * KS) * R + r;
    const float* __restrict__ Ab0 = A + (size_t)w0 * (K * R) + koff;
    const float* __restrict__ Ab1 = A + (size_t)w1 * (K * R) + koff;
    const float* __restrict__ Ab2 = A + (size_t)w2 * (K * R) + koff;
    const float* __restrict__ Ab3 = A + (size_t)w3 * (K * R) + koff;
    const bool uniform = (w0 == w3);   // perm is wid-sorted

    float acc0 = 0.f, acc1 = 0.f, acc2 = 0.f, acc3 = 0.f;

#define DOT8(ACC, V, AP) do {                                              \
        ACC = fmaf(bflo((V).x), (AP)[0], ACC);                             \
        ACC = fmaf(bfhi((V).x), (AP)[1], ACC);                             \
        ACC = fmaf(bflo((V).y), (AP)[2], ACC);                             \
        ACC = fmaf(bfhi((V).y), (AP)[3], ACC);                             \
        ACC = fmaf(bflo((V).z), (AP)[4], ACC);                             \
        ACC = fmaf(bfhi((V).z), (AP)[5], ACC);                             \
        ACC = fmaf(bflo((V).w), (AP)[6], ACC);                             \
        ACC = fmaf(bfhi((V).w), (AP)[7], ACC);                             \
    } while (0)

    // prologue: stage tile 0 into buf 0
    uint4 p0, p1, p2, p3;
    {
        const uint4* src = (const uint4*)xrow;
        p0 = src[0]; p1 = src[1]; p2 = src[2]; p3 = src[3];
        uint32_t* wb = &xs[0][cc * 1024 + 4 * r];
        *(uint4*)(wb +   0) = p0;
        *(uint4*)(wb + 256) = p1;
        *(uint4*)(wb + 512) = p2;
        *(uint4*)(wb + 768) = p3;
    }

    for (int tile = 0; tile < NTILE; ++tile) {
        if (tile + 1 < NTILE) {   // prefetch next tile's line into regs
            const uint4* src = (const uint4*)(xrow + (tile + 1) * TK);
            p0 = src[0]; p1 = src[1]; p2 = src[2]; p3 = src[3];
        }
        __syncthreads();          // tile's writes visible; prev readers done

        const uint32_t* __restrict__ B = &xs[tile & 1][wv * 256 + 4 * r];
        const size_t ao = (size_t)(tile * TK + wv * 8) * R;
        const uint4 x0 = *(const uint4*)(B + 0 * 1024);
        const uint4 x1 = *(const uint4*)(B + 1 * 1024);
        const uint4 x2 = *(const uint4*)(B + 2 * 1024);
        const uint4 x3 = *(const uint4*)(B + 3 * 1024);

        if (uniform) {
            const float* At = Ab0 + ao;
            float a[8];
#pragma unroll
            for (int q = 0; q < 8; ++q) a[q] = At[(size_t)q * R];
            DOT8(acc0, x0, a);
            DOT8(acc1, x1, a);
            DOT8(acc2, x2, a);
            DOT8(acc3, x3, a);
        } else {
            {
                const float* At = Ab0 + ao; float a[8];
#pragma unroll
                for (int q = 0; q < 8; ++q) a[q] = At[(size_t)q * R];
                DOT8(acc0, x0, a);
            }
            {
                const float* At = Ab1 + ao; float a[8];
#pragma unroll
                for (int q = 0; q < 8; ++q) a[q] = At[(size_t)q * R];
                DOT8(acc1, x1, a);
            }
            {
                const float* At = Ab2 + ao; float a[8];
#pragma unroll
                for (int q = 0; q < 8; ++q) a[q] = At[(size_t)q * R];
                DOT8(acc2, x2, a);
            }
            {
                const float* At = Ab3 + ao; float a[8];
#pragma unroll
                for (int q = 0; q < 8; ++q) a[q] = At[(size_t)q * R];
                DOT8(acc3, x3, a);
            }
        }

        if (tile + 1 < NTILE) {   // write prefetched tile into other buffer
            uint32_t* wb = &xs[(tile + 1) & 1][cc * 1024 + 4 * r];
            *(uint4*)(wb +   0) = p0;
            *(uint4*)(wb + 256) = p1;
            *(uint4*)(wb + 512) = p2;
            *(uint4*)(wb + 768) = p3;
        }
    }
#undef DOT8

    // ---- cross-wave reduce: red[wv][c][r]; wave wv finalizes combo wv ----
    red[wv * 256 +   0 + r] = acc0;
    red[wv * 256 +  64 + r] = acc1;
    red[wv * 256 + 128 + r] = acc2;
    red[wv * 256 + 192 + r] = acc3;
    __syncthreads();
    const float sum = red[0 * 256 + wv * 64 + r] + red[1 * 256 + wv * 64 + r] +
                      red[2 * 256 + wv * 64 + r] + red[3 * 256 + wv * 64 + r];
    atomicAdd(&out[ccombo * R + r], sum);
}

// ---- fallback (ws too small): fp32 x from global, LDS transpose, no perm ----
__global__ __launch_bounds__(NT)
void lora_fallback(const float* __restrict__ x,
                   const int*   __restrict__ xids,
                   const int*   __restrict__ wids,
                   const float* __restrict__ A,
                   float*       __restrict__ out)
{
    constexpr int FKS = 512, FTK = 64, FNT_TILES = 8, FNW = 4;
    __shared__ float xsf[FTK * R];
    __shared__ float red[FNW * R];
    const int bid  = blockIdx.x;
    const int c    = bid >> 3;
    const int s    = bid & 7;
    const int t    = threadIdx.x;
    const int wave = t >> 6;
    const int lane = t & 63;
    const int r4   = lane & 15;
    const int kq   = lane >> 4;
    const int wid  = wids[c];
    const float* __restrict__ Aw = A + (size_t)wid * (K * R);
    const int rw  = t >> 2;
    const int jq  = t & 3;
    const int tok = xids[c * R + rw];
    const float* __restrict__ xrow = x + (size_t)tok * K + s * FKS + jq * 16;
    float4 acc = make_float4(0.f, 0.f, 0.f, 0.f);
    float4 pv[4];
    {
        const float4* src = (const float4*)xrow;
#pragma unroll
        for (int ii = 0; ii < 4; ++ii) pv[ii] = src[ii];
    }
    for (int tile = 0; tile < FNT_TILES; ++tile) {
#pragma unroll
        for (int ii = 0; ii < 4; ++ii) {
            const int kk = jq * 16 + ii * 4;
            xsf[(kk + 0) * R + rw] = pv[ii].x;
            xsf[(kk + 1) * R + rw] = pv[ii].y;
            xsf[(kk + 2) * R + rw] = pv[ii].z;
            xsf[(kk + 3) * R + rw] = pv[ii].w;
        }
        __syncthreads();
        if (tile + 1 < FNT_TILES) {
            const float4* src = (const float4*)(xrow + (tile + 1) * FTK);
#pragma unroll
            for (int ii = 0; ii < 4; ++ii) pv[ii] = src[ii];
        }
        const int kw = wave * 16 + kq;
        const float* __restrict__ Ap =
            Aw + (size_t)(s * FKS + tile * FTK + kw) * R + 4 * r4;
#pragma unroll
        for (int i = 0; i < 4; ++i) {
            float4 av = *(const float4*)(Ap + (size_t)(4 * i) * R);
            float4 xv = *(const float4*)(&xsf[(kw + 4 * i) * R + 4 * r4]);
            acc.x = fmaf(xv.x, av.x, acc.x);
            acc.y = fmaf(xv.y, av.y, acc.y);
            acc.z = fmaf(xv.z, av.z, acc.z);
            acc.w = fmaf(xv.w, av.w, acc.w);
        }
        __syncthreads();
    }
#pragma unroll
    for (int m = 16; m < 64; m <<= 1) {
        acc.x += __shfl_xor(acc.x, m, 64);
        acc.y += __shfl_xor(acc.y, m, 64);
        acc.z += __shfl_xor(acc.z, m, 64);
        acc.w += __shfl_xor(acc.w, m, 64);
    }
    if (kq == 0) {
        float* rd = &red[wave * R + 4 * r4];
        rd[0] = acc.x; rd[1] = acc.y; rd[2] = acc.z; rd[3] = acc.w;
    }
    __syncthreads();
    if (wave == 0) {
        float sum = red[lane] + red[R + lane] + red[2 * R + lane] + red[3 * R + lane];
        atomicAdd(&out[c * R + lane], sum);
    }
}

extern "C" void kernel_launch(void* const* d_in, const int* in_sizes, int n_in,
                              void* d_out, int out_size, void* d_ws, size_t ws_size,
                              hipStream_t stream)
{
    (void)in_sizes; (void)n_in;
    const float* x    = (const float*)d_in[0];
    const int*   xids = (const int*)d_in[1];
    const int*   wids = (const int*)d_in[2];
    const float* A    = (const float*)d_in[3];
    float* out        = (float*)d_out;

    if (ws_size >= WS_NEEDED) {
        int*      perm = (int*)d_ws;
        uint16_t* xbw  = (uint16_t*)((char*)d_ws + WS_X_OFF);
        const int ncvt = BATCH * K / 1024;              // 2048
        const int nz   = (out_size + 1023) / 1024;      // out-zero blocks
        hipLaunchKernelGGL(prep, dim3(1 + ncvt + nz), dim3(256), 0, stream,
                           x, xbw, wids, perm, out, out_size);
        hipLaunchKernelGGL(lora_main, dim3(NGRP * SPLIT), dim3(NT), 0, stream,
                           xids, wids, A, xbw, perm, out);
    } else {
        hipMemsetAsync(out, 0, (size_t)out_size * sizeof(float), stream);
        hipLaunchKernelGGL(lora_fallback, dim3(CBS * 8), dim3(NT), 0, stream,
                           x, xids, wids, A, out);
    }
}

// Round 4
// 158.104 us; speedup vs baseline: 1.1380x; 1.0117x over previous
//
#include <hip/hip_runtime.h>
#include <stdint.h>

namespace {
constexpr int BATCH  = 512;
constexpr int CBS    = 320;       // combined batch size
constexpr int R      = 64;        // rank
constexpr int K      = 4096;
constexpr int NADAPT = 80;
constexpr int GRP    = 4;         // combos per block (always wid-uniform now)
constexpr int NGMAX  = 140;       // max groups: sum ceil(cnt/4) <= (320+3*80)/4
constexpr int SPLIT  = 16;        // k-slices
constexpr int KS     = K / SPLIT; // 256 k per block
constexpr int TK     = 32;        // k per LDS tile
constexpr int NTILE  = KS / TK;   // 8
constexpr int NT     = 256;       // 4 waves

// ws layout: hdr[16] ints at 0 (hdr[0]=ng); grp[NGMAX*4] ints at byte 64;
// x_bf16[512][4096] at byte 4096
constexpr size_t WS_GRP_OFF = 64;
constexpr size_t WS_X_OFF   = 4096;
constexpr size_t WS_NEEDED  = WS_X_OFF + (size_t)BATCH * K * 2;  // ~4.2 MiB

__device__ inline uint16_t f2bf(float f) {   // RNE fp32 -> bf16
    uint32_t u = __float_as_uint(f);
    u += 0x7fffu + ((u >> 16) & 1u);
    return (uint16_t)(u >> 16);
}
__device__ inline float bflo(uint32_t u) { return __uint_as_float(u << 16); }
__device__ inline float bfhi(uint32_t u) { return __uint_as_float(u & 0xffff0000u); }

__device__ __forceinline__ void dot8(float& acc, const uint4 v, const float (&a)[8]) {
    acc = fmaf(bflo(v.x), a[0], acc);
    acc = fmaf(bfhi(v.x), a[1], acc);
    acc = fmaf(bflo(v.y), a[2], acc);
    acc = fmaf(bfhi(v.y), a[3], acc);
    acc = fmaf(bflo(v.z), a[4], acc);
    acc = fmaf(bfhi(v.z), a[5], acc);
    acc = fmaf(bflo(v.w), a[6], acc);
    acc = fmaf(bfhi(v.w), a[7], acc);
}

#define WAITL() asm volatile("s_waitcnt lgkmcnt(0)" ::: "memory")
#define SCHED0() __builtin_amdgcn_sched_barrier(0)
#define SBAR()  __builtin_amdgcn_s_barrier()

// One pipelined tile. Steady-state invariant entering: 12 outstanding vmem
// (4 x-dwordx4 for tile T+1, 8 A-dwords for tile T). Issue next 12, then
// s_waitcnt vmcnt(WN) retires exactly the previous 12 (FIFO, m135), leaving
// the new 12 in flight ACROSS the raw barrier -- never drained in-loop.
template<int T, bool IX2, bool IA1, bool WRT, int WN>
__device__ __forceinline__ void body(
    uint32_t* __restrict__ xs_base,          // xs[2][4096] flattened
    const uint16_t* __restrict__ xrow,
    const float* __restrict__ Ab,
    int wv, int r,
    uint4 (&pxN)[4], const uint4 (&pxW)[4],
    float (&aN)[8], const float (&aC)[8],
    float& acc0, float& acc1, float& acc2, float& acc3)
{
    const uint32_t* Bp = xs_base + (T & 1) * 4096 + wv * 256 + 4 * r;
    const uint4 xv0 = *(const uint4*)(Bp + 0 * 1024);
    const uint4 xv1 = *(const uint4*)(Bp + 1 * 1024);
    const uint4 xv2 = *(const uint4*)(Bp + 2 * 1024);
    const uint4 xv3 = *(const uint4*)(Bp + 3 * 1024);
    if constexpr (IX2) {                         // issue x(T+2) -> pxN
        const uint4* s2 = (const uint4*)(xrow + (T + 2) * TK);
        pxN[0] = s2[0]; pxN[1] = s2[1]; pxN[2] = s2[2]; pxN[3] = s2[3];
    }
    if constexpr (IA1) {                         // issue A(T+1) -> aN
#pragma unroll
        for (int q = 0; q < 8; ++q)
            aN[q] = Ab[((size_t)((T + 1) * TK) + wv * 8 + q) * R];
    }
    asm volatile("s_waitcnt vmcnt(%0)" :: "i"(WN) : "memory");  // A(T),x(T+1) landed
    WAITL();                                      // ds_reads landed
    SCHED0();
    dot8(acc0, xv0, aC);
    dot8(acc1, xv1, aC);
    dot8(acc2, xv2, aC);
    dot8(acc3, xv3, aC);
    if constexpr (WRT) {                          // write x(T+1) into other buf
        uint32_t* wb = xs_base + ((T + 1) & 1) * 4096 + wv * 1024 + 4 * r;
        *(uint4*)(wb +   0) = pxW[0];
        *(uint4*)(wb + 256) = pxW[1];
        *(uint4*)(wb + 512) = pxW[2];
        *(uint4*)(wb + 768) = pxW[3];
        WAITL(); SCHED0();
        SBAR();                                   // raw barrier: no vmcnt drain
        SCHED0();
    }
}
}

// ---- pre-pass (fused): block 0 = wid-sort + per-adapter group build;
//      blocks 1..2048 = x fp32->bf16; trailing blocks zero `out` ----
__global__ __launch_bounds__(256)
void prep(const float* __restrict__ x, uint16_t* __restrict__ xb,
          const int* __restrict__ wids, int* __restrict__ hdr,
          int* __restrict__ grp, float* __restrict__ out, int out_size)
{
    const int bid = blockIdx.x;
    const int t   = threadIdx.x;
    if (bid == 0) {
        __shared__ int hist[NADAPT];
        __shared__ int offs[NADAPT];
        __shared__ int gbase[NADAPT + 1];
        __shared__ int sperm[CBS];
        if (t < NADAPT) hist[t] = 0;
        __syncthreads();
        for (int c = t; c < CBS; c += 256) atomicAdd(&hist[wids[c]], 1);
        __syncthreads();
        if (t == 0) {
            int run = 0, grun = 0;
            for (int i = 0; i < NADAPT; ++i) {
                offs[i]  = run;  run  += hist[i];
                gbase[i] = grun; grun += (hist[i] + GRP - 1) / GRP;
            }
            gbase[NADAPT] = grun;
            hdr[0] = grun;                 // ng
        }
        __syncthreads();
        for (int c = t; c < CBS; c += 256) {
            const int pos = atomicAdd(&offs[wids[c]], 1);
            sperm[pos] = c;
        }
        __syncthreads();
        for (int w = t; w < NADAPT; w += 256) {   // emit uniform groups (pad -1)
            const int cnt   = hist[w];
            const int start = offs[w] - cnt;      // cursor ended at start+cnt
            const int gb    = gbase[w];
            for (int i = 0; i < cnt; i += GRP) {
                const int gi = gb + i / GRP;
#pragma unroll
                for (int j = 0; j < GRP; ++j)
                    grp[GRP * gi + j] = (i + j < cnt) ? sperm[start + i + j] : -1;
            }
        }
    } else if (bid <= BATCH * K / 1024) {          // 2048 cvt blocks
        const int i = (bid - 1) * 256 + t;
        const float4 v = ((const float4*)x)[i];
        ushort4 o;
        o.x = f2bf(v.x); o.y = f2bf(v.y); o.z = f2bf(v.z); o.w = f2bf(v.w);
        ((ushort4*)xb)[i] = o;
    } else {                                       // zero out[]
        const int i4 = (bid - (1 + BATCH * K / 1024)) * 256 + t;
        const int e  = i4 * 4;
        if (e + 3 < out_size) {
            ((float4*)out)[i4] = make_float4(0.f, 0.f, 0.f, 0.f);
        } else {
            for (int q = e; q < out_size; ++q) out[q] = 0.f;
        }
    }
}

// ---- main: block (g, s) = one wid-uniform group (<=4 combos) x 256-k slice.
// T3/T4 pipeline: raw s_barrier + counted vmcnt; x global->reg->LDS 2 tiles
// deep, A global->reg 1 tile deep (named ping-pong sets). Loads are never
// drained inside the loop (WN=12 steady / 8 / 0 at tail). Padded slots stage
// duplicate x and are masked at the final atomic.
__global__ __launch_bounds__(NT, 4)
void lora_main(const int* __restrict__ xids,
               const int* __restrict__ wids,
               const float* __restrict__ A,
               const uint16_t* __restrict__ xb,
               const int* __restrict__ hdr,
               const int* __restrict__ grp,
               float* __restrict__ out)
{
    __shared__ __align__(16) uint32_t xs[2][GRP * 1024];  // 2 x 16 KiB
    __shared__ float red[4 * GRP * 64];                   // 4 KiB

    const int bid = blockIdx.x;
    const int g   = bid >> 4;
    const int s   = bid & 15;
    if (g >= hdr[0]) return;                // inactive tail blocks (uniform exit)

    const int t  = threadIdx.x;
    const int wv = t >> 6;
    const int r  = t & 63;

    const int* gp = grp + GRP * g;
    const int gc0 = gp[0], gc1 = gp[1], gc2 = gp[2], gc3 = gp[3];
    const int myc_raw = (wv == 0) ? gc0 : (wv == 1) ? gc1 : (wv == 2) ? gc2 : gc3;
    const int myc = (myc_raw >= 0) ? myc_raw : gc0;     // pad slots stage dup x
    const int wid = wids[gc0];                          // group is wid-uniform

    const uint16_t* __restrict__ xrow = xb + (size_t)xids[myc * R + r] * K + s * KS;
    const float* __restrict__ Ab = A + (size_t)wid * (K * R) + (size_t)(s * KS) * R + r;

    float acc0 = 0.f, acc1 = 0.f, acc2 = 0.f, acc3 = 0.f;
    uint4 pxA[4], pxB[4];
    float aA[8], aB[8];

    // ---- prologue: x(0)->pxA, x(1)->pxB, A(0)->aA; pin issue order ----
    {
        const uint4* s0p = (const uint4*)xrow;
        pxA[0] = s0p[0]; pxA[1] = s0p[1]; pxA[2] = s0p[2]; pxA[3] = s0p[3];
        SCHED0();
        const uint4* s1p = (const uint4*)(xrow + TK);
        pxB[0] = s1p[0]; pxB[1] = s1p[1]; pxB[2] = s1p[2]; pxB[3] = s1p[3];
        SCHED0();
#pragma unroll
        for (int q = 0; q < 8; ++q) aA[q] = Ab[(size_t)(wv * 8 + q) * R];
        asm volatile("s_waitcnt vmcnt(12)" ::: "memory");   // x(0) landed
        uint32_t* wb = &xs[0][wv * 1024 + 4 * r];
        *(uint4*)(wb +   0) = pxA[0];
        *(uint4*)(wb + 256) = pxA[1];
        *(uint4*)(wb + 512) = pxA[2];
        *(uint4*)(wb + 768) = pxA[3];
        WAITL(); SCHED0();
        SBAR();
        SCHED0();
    }
    // entering loop: 12 outstanding = x(1)4 + A(0)8

    uint32_t* xsb = &xs[0][0];
    body<0, true,  true,  true, 12>(xsb, xrow, Ab, wv, r, pxA, pxB, aB, aA, acc0, acc1, acc2, acc3);
    body<1, true,  true,  true, 12>(xsb, xrow, Ab, wv, r, pxB, pxA, aA, aB, acc0, acc1, acc2, acc3);
    body<2, true,  true,  true, 12>(xsb, xrow, Ab, wv, r, pxA, pxB, aB, aA, acc0, acc1, acc2, acc3);
    body<3, true,  true,  true, 12>(xsb, xrow, Ab, wv, r, pxB, pxA, aA, aB, acc0, acc1, acc2, acc3);
    body<4, true,  true,  true, 12>(xsb, xrow, Ab, wv, r, pxA, pxB, aB, aA, acc0, acc1, acc2, acc3);
    body<5, true,  true,  true, 12>(xsb, xrow, Ab, wv, r, pxB, pxA, aA, aB, acc0, acc1, acc2, acc3);
    body<6, false, true,  true,  8>(xsb, xrow, Ab, wv, r, pxA, pxB, aB, aA, acc0, acc1, acc2, acc3);
    body<7, false, false, false, 0>(xsb, xrow, Ab, wv, r, pxB, pxA, aA, aB, acc0, acc1, acc2, acc3);

    // ---- cross-wave reduce: red[srcwave][slot][r]; wave wv finalizes slot wv ----
    red[wv * 256 +   0 + r] = acc0;
    red[wv * 256 +  64 + r] = acc1;
    red[wv * 256 + 128 + r] = acc2;
    red[wv * 256 + 192 + r] = acc3;
    __syncthreads();
    const float sum = red[0 * 256 + wv * 64 + r] + red[1 * 256 + wv * 64 + r] +
                      red[2 * 256 + wv * 64 + r] + red[3 * 256 + wv * 64 + r];
    if (myc_raw >= 0)
        atomicAdd(&out[myc_raw * R + r], sum);
}

// ---- fallback (ws too small): fp32 x from global, LDS transpose, no perm ----
__global__ __launch_bounds__(NT)
void lora_fallback(const float* __restrict__ x,
                   const int*   __restrict__ xids,
                   const int*   __restrict__ wids,
                   const float* __restrict__ A,
                   float*       __restrict__ out)
{
    constexpr int FKS = 512, FTK = 64, FNT_TILES = 8, FNW = 4;
    __shared__ float xsf[FTK * R];
    __shared__ float red[FNW * R];
    const int bid  = blockIdx.x;
    const int c    = bid >> 3;
    const int s    = bid & 7;
    const int t    = threadIdx.x;
    const int wave = t >> 6;
    const int lane = t & 63;
    const int r4   = lane & 15;
    const int kq   = lane >> 4;
    const int wid  = wids[c];
    const float* __restrict__ Aw = A + (size_t)wid * (K * R);
    const int rw  = t >> 2;
    const int jq  = t & 3;
    const int tok = xids[c * R + rw];
    const float* __restrict__ xrow = x + (size_t)tok * K + s * FKS + jq * 16;
    float4 acc = make_float4(0.f, 0.f, 0.f, 0.f);
    float4 pv[4];
    {
        const float4* src = (const float4*)xrow;
#pragma unroll
        for (int ii = 0; ii < 4; ++ii) pv[ii] = src[ii];
    }
    for (int tile = 0; tile < FNT_TILES; ++tile) {
#pragma unroll
        for (int ii = 0; ii < 4; ++ii) {
            const int kk = jq * 16 + ii * 4;
            xsf[(kk + 0) * R + rw] = pv[ii].x;
            xsf[(kk + 1) * R + rw] = pv[ii].y;
            xsf[(kk + 2) * R + rw] = pv[ii].z;
            xsf[(kk + 3) * R + rw] = pv[ii].w;
        }
        __syncthreads();
        if (tile + 1 < FNT_TILES) {
            const float4* src = (const float4*)(xrow + (tile + 1) * FTK);
#pragma unroll
            for (int ii = 0; ii < 4; ++ii) pv[ii] = src[ii];
        }
        const int kw = wave * 16 + kq;
        const float* __restrict__ Ap =
            Aw + (size_t)(s * FKS + tile * FTK + kw) * R + 4 * r4;
#pragma unroll
        for (int i = 0; i < 4; ++i) {
            float4 av = *(const float4*)(Ap + (size_t)(4 * i) * R);
            float4 xv = *(const float4*)(&xsf[(kw + 4 * i) * R + 4 * r4]);
            acc.x = fmaf(xv.x, av.x, acc.x);
            acc.y = fmaf(xv.y, av.y, acc.y);
            acc.z = fmaf(xv.z, av.z, acc.z);
            acc.w = fmaf(xv.w, av.w, acc.w);
        }
        __syncthreads();
    }
#pragma unroll
    for (int m = 16; m < 64; m <<= 1) {
        acc.x += __shfl_xor(acc.x, m, 64);
        acc.y += __shfl_xor(acc.y, m, 64);
        acc.z += __shfl_xor(acc.z, m, 64);
        acc.w += __shfl_xor(acc.w, m, 64);
    }
    if (kq == 0) {
        float* rd = &red[wave * R + 4 * r4];
        rd[0] = acc.x; rd[1] = acc.y; rd[2] = acc.z; rd[3] = acc.w;
    }
    __syncthreads();
    if (wave == 0) {
        float sum = red[lane] + red[R + lane] + red[2 * R + lane] + red[3 * R + lane];
        atomicAdd(&out[c * R + lane], sum);
    }
}

extern "C" void kernel_launch(void* const* d_in, const int* in_sizes, int n_in,
                              void* d_out, int out_size, void* d_ws, size_t ws_size,
                              hipStream_t stream)
{
    (void)in_sizes; (void)n_in;
    const float* x    = (const float*)d_in[0];
    const int*   xids = (const int*)d_in[1];
    const int*   wids = (const int*)d_in[2];
    const float* A    = (const float*)d_in[3];
    float* out        = (float*)d_out;

    if (ws_size >= WS_NEEDED) {
        int*      hdr = (int*)d_ws;
        int*      grp = (int*)((char*)d_ws + WS_GRP_OFF);
        uint16_t* xbw = (uint16_t*)((char*)d_ws + WS_X_OFF);
        const int ncvt = BATCH * K / 1024;              // 2048
        const int nz   = (out_size + 1023) / 1024;      // out-zero blocks
        hipLaunchKernelGGL(prep, dim3(1 + ncvt + nz), dim3(256), 0, stream,
                           x, xbw, wids, hdr, grp, out, out_size);
        hipLaunchKernelGGL(lora_main, dim3(NGMAX * SPLIT), dim3(NT), 0, stream,
                           xids, wids, A, xbw, hdr, grp, out);
    } else {
        hipMemsetAsync(out, 0, (size_t)out_size * sizeof(float), stream);
        hipLaunchKernelGGL(lora_fallback, dim3(CBS * 8), dim3(NT), 0, stream,
                           x, xids, wids, A, out);
    }
}